// Round 12
// baseline (103.750 us; speedup 1.0000x reference)
//
#include <hip/hip_runtime.h>

#define IDX_BASE 16777216UL   // 4096*64*64
#define LOSS_IDX 17039360UL   // IDX_BASE + 4096*64
#define EPS2 0.02f            // rescue window on (M1 - M2); score err bound ~1e-3

typedef float4 f4;
typedef _Float16 half8 __attribute__((ext_vector_type(8)));
typedef float f32x4 __attribute__((ext_vector_type(4)));

// ---- precompute code A-fragments (f16 hi/lo) + fused c2 table.
//      unit u = tile*4 + s*2 + hl; fragbuf[m][u][lane] : half8 ----
__global__ __launch_bounds__(256) void pq_frag(const float* __restrict__ cb,
                                               half8* __restrict__ fragbuf,
                                               float* __restrict__ c2) {
    int m = blockIdx.x, tid = threadIdx.x;
    int w = tid >> 6, lane = tid & 63, lh = lane >> 4, l15 = lane & 15;
    const float* cbm = cb + (size_t)m * (256 * 64);
    half8* fbm = fragbuf + (size_t)m * (16 * 4 * 64);
    #pragma unroll
    for (int ti = 0; ti < 4; ++ti) {
        int tile = w * 4 + ti;
        int code = tile * 16 + l15;
        const float* crow = cbm + code * 64 + lh * 8;
        float ss = 0.f;
        #pragma unroll
        for (int s = 0; s < 2; ++s) {
            f4 a = *reinterpret_cast<const f4*>(crow + s * 32);
            f4 b = *reinterpret_cast<const f4*>(crow + s * 32 + 4);
            float v[8] = {a.x, a.y, a.z, a.w, b.x, b.y, b.z, b.w};
            half8 hi, lo;
            #pragma unroll
            for (int e = 0; e < 8; ++e) {
                _Float16 h = (_Float16)v[e];
                hi[e] = h; lo[e] = (_Float16)(v[e] - (float)h);
                ss = fmaf(v[e], v[e], ss);
            }
            fbm[(tile * 4 + s * 2 + 0) * 64 + lane] = hi;
            fbm[(tile * 4 + s * 2 + 1) * 64 + lane] = lo;
        }
        // c2: 4 lh-lanes hold disjoint 16-dim partials of the same code
        ss += __shfl_xor(ss, 16, 64);
        ss += __shfl_xor(ss, 32, 64);
        if (lh == 0) c2[m * 256 + code] = ss;
    }
}

// ---- main: NO LDS, NO barriers; wave = 32 rows x all 256 codes.
//      z f16-frags resident (32 VGPR); A-frags streamed from L2-hot fragbuf. ----
__global__ __launch_bounds__(256, 4) void pq_main(
    const float* __restrict__ z, const float* __restrict__ cb,
    const float* __restrict__ c2ws, const half8* __restrict__ fragbuf,
    float* __restrict__ out, float* __restrict__ partial)
{
    const int tid = threadIdx.x, bx = blockIdx.x;
    // XCD-aware: bx&7 (XCD) picks an m-octet -> per-XCD L2 set = 8 codebooks+frags
    const int m = ((bx & 7) << 3) | ((bx >> 3) & 7);
    const int chunk = bx >> 6;                   // 0..31
    const int w = tid >> 6, lane = tid & 63;
    const int lh = lane >> 4, l15 = lane & 15;
    const int rowbase = chunk * 128 + w * 32;

    const float* __restrict__ cbm = cb + (size_t)m * (256 * 64);
    const f4* cb4m = reinterpret_cast<const f4*>(cbm);
    const half8* __restrict__ fb = fragbuf + (size_t)m * (16 * 4 * 64);
    const f4* __restrict__ c2t = reinterpret_cast<const f4*>(c2ws + m * 256);

    // ---- resident z B-fragments (R10-validated conversion) ----
    half8 zh0[2], zl0[2], zh1[2], zl1[2];
    #pragma unroll
    for (int h = 0; h < 2; ++h) {
        size_t rh = (size_t)(rowbase + h * 16 + l15);
        const float* zb = z + (rh * 64 + m) * 64 + lh * 8;
        f4 p0 = *reinterpret_cast<const f4*>(zb);
        f4 p1 = *reinterpret_cast<const f4*>(zb + 4);
        f4 p2 = *reinterpret_cast<const f4*>(zb + 32);
        f4 p3 = *reinterpret_cast<const f4*>(zb + 36);
        float v0[8] = {p0.x,p0.y,p0.z,p0.w,p1.x,p1.y,p1.z,p1.w};
        float v1[8] = {p2.x,p2.y,p2.z,p2.w,p3.x,p3.y,p3.z,p3.w};
        #pragma unroll
        for (int e = 0; e < 8; ++e) {
            _Float16 a = (_Float16)v0[e];
            zh0[h][e] = a; zl0[h][e] = (_Float16)(v0[e] - (float)a);
            _Float16 b = (_Float16)v1[e];
            zh1[h][e] = b; zl1[h][e] = (_Float16)(v1[e] - (float)b);
        }
    }

    float m1[2] = {-1e30f, -1e30f}, m2[2] = {-1e30f, -1e30f};
    int   bk[2] = {0, 0};

    // ---- 16 independent code-tiles: 4 coalesced frag loads + c2 + 12 MFMA ----
    #pragma unroll 4
    for (int tile = 0; tile < 16; ++tile) {
        half8 ah0 = fb[(tile * 4 + 0) * 64 + lane];
        half8 al0 = fb[(tile * 4 + 1) * 64 + lane];
        half8 ah1 = fb[(tile * 4 + 2) * 64 + lane];
        half8 al1 = fb[(tile * 4 + 3) * 64 + lane];
        f4 cv = c2t[tile * 4 + lh];
        f32x4 ci; ci[0] = -0.5f*cv.x; ci[1] = -0.5f*cv.y; ci[2] = -0.5f*cv.z; ci[3] = -0.5f*cv.w;
        #pragma unroll
        for (int h = 0; h < 2; ++h) {
            f32x4 acc = ci;
            acc = __builtin_amdgcn_mfma_f32_16x16x32_f16(ah0, h ? zh0[1] : zh0[0], acc, 0, 0, 0);
            acc = __builtin_amdgcn_mfma_f32_16x16x32_f16(ah1, h ? zh1[1] : zh1[0], acc, 0, 0, 0);
            acc = __builtin_amdgcn_mfma_f32_16x16x32_f16(ah0, h ? zl0[1] : zl0[0], acc, 0, 0, 0);
            acc = __builtin_amdgcn_mfma_f32_16x16x32_f16(ah1, h ? zl1[1] : zl1[0], acc, 0, 0, 0);
            acc = __builtin_amdgcn_mfma_f32_16x16x32_f16(al0, h ? zh0[1] : zh0[0], acc, 0, 0, 0);
            acc = __builtin_amdgcn_mfma_f32_16x16x32_f16(al1, h ? zh1[1] : zh1[0], acc, 0, 0, 0);
            #pragma unroll
            for (int r = 0; r < 4; ++r) {
                float v = acc[r];
                int code = tile * 16 + lh * 4 + r;
                m2[h] = __builtin_amdgcn_fmed3f(v, m1[h], m2[h]);  // == max(m2,min(v,m1))
                bool gt = v > m1[h];
                m1[h] = gt ? v : m1[h];
                bk[h] = gt ? code : bk[h];
            }
        }
    }

    // ---- per row-tile: merge 4 lane-groups, rescue (rare), epilogue ----
    float lsum = 0.f;
    #pragma unroll
    for (int h = 0; h < 2; ++h) {
        #pragma unroll
        for (int off = 16; off <= 32; off <<= 1) {       // validated merge
            float om1 = __shfl_xor(m1[h], off, 64);
            float om2 = __shfl_xor(m2[h], off, 64);
            int   obk = __shfl_xor(bk[h], off, 64);
            m2[h] = fmaxf(fmaxf(m2[h], om2), fminf(m1[h], om1));
            bool better = (om1 > m1[h]) || (om1 == m1[h] && obk < bk[h]);
            m1[h] = better ? om1 : m1[h];
            bk[h] = better ? obk : bk[h];
        }
        // rescue: exact fp32 rescan (validated R4 arithmetic), z from global
        bool need = (m1[h] - m2[h] < EPS2);
        unsigned mask = (unsigned)(__ballot(need)) & 0xFFFFu;
        while (mask) {
            int row = __builtin_ctz(mask); mask &= mask - 1;
            size_t rg = (size_t)(rowbase + h * 16 + row);
            const f4* zr4 = reinterpret_cast<const f4*>(z + (rg * 64 + m) * 64);
            float bs = -1e30f; int bkx = 0;
            #pragma unroll 1
            for (int j = 0; j < 4; ++j) {
                int k = j * 64 + lane;
                float s = -0.5f * c2ws[m * 256 + k];
                #pragma unroll
                for (int d4 = 0; d4 < 16; ++d4) {
                    f4 c = cb4m[k * 16 + d4];
                    f4 zz = zr4[d4];
                    s = fmaf(zz.x, c.x, s); s = fmaf(zz.y, c.y, s);
                    s = fmaf(zz.z, c.z, s); s = fmaf(zz.w, c.w, s);
                }
                if (s > bs) { bs = s; bkx = k; }
            }
            #pragma unroll
            for (int off = 1; off < 64; off <<= 1) {
                float ov = __shfl_xor(bs, off, 64);
                int   ok = __shfl_xor(bkx, off, 64);
                if (ov > bs || (ov == bs && ok < bkx)) { bs = ov; bkx = ok; }
            }
            bk[h] = (l15 == row) ? bkx : bk[h];
        }
        // ---- epilogue, redistributed: lane = (row rloc, quarter q) ->
        //      one contiguous 64 B store per lane (clean write-combining) ----
        {
            int rloc = lane >> 2, q = lane & 3;
            int bkr = __shfl(bk[h], rloc, 64);           // bk lives on lane rloc (lh=0)
            size_t rg = (size_t)(rowbase + h * 16 + rloc);
            const f4* qb  = cb4m + (size_t)bkr * 16 + q * 4;
            const f4* zb4 = reinterpret_cast<const f4*>(z + (rg * 64 + m) * 64) + q * 4;
            f4*       ob  = reinterpret_cast<f4*>(out + (rg * 64 + m) * 64) + q * 4;
            float l0 = 0.f, l1 = 0.f;
            #pragma unroll
            for (int e = 0; e < 4; ++e) {
                f4 qv = qb[e], zv = zb4[e];              // exact codebook copy, exact z
                ob[e] = qv;
                float d0 = qv.x - zv.x, d1 = qv.y - zv.y;
                float d2 = qv.z - zv.z, d3 = qv.w - zv.w;
                l0 = fmaf(d0, d0, l0); l1 = fmaf(d1, d1, l1);
                l0 = fmaf(d2, d2, l0); l1 = fmaf(d3, d3, l1);
            }
            lsum += l0 + l1;
        }
        if (lane < 16)
            out[IDX_BASE + (size_t)(rowbase + h * 16 + lane) * 64 + m] = (float)bk[h];
    }

    // ---- per-wave loss partial (no barrier, no LDS) ----
    #pragma unroll
    for (int off = 1; off < 64; off <<= 1) lsum += __shfl_xor(lsum, off, 64);
    if (lane == 0) partial[bx * 4 + w] = lsum;
}

// ---- deterministic final reduction of 8192 wave partials -> q_loss ----
__global__ __launch_bounds__(256) void pq_loss(const float* __restrict__ partial,
                                               float* __restrict__ out)
{
    __shared__ float sW[4];
    float s = 0.f;
    #pragma unroll
    for (int i = 0; i < 32; ++i) s += partial[threadIdx.x + i * 256];
    #pragma unroll
    for (int off = 1; off < 64; off <<= 1) s += __shfl_xor(s, off, 64);
    if ((threadIdx.x & 63) == 0) sW[threadIdx.x >> 6] = s;
    __syncthreads();
    if (threadIdx.x == 0)
        out[LOSS_IDX] = ((sW[0] + sW[1]) + (sW[2] + sW[3])) * (1.25f / 16777216.0f);
}

extern "C" void kernel_launch(void* const* d_in, const int* in_sizes, int n_in,
                              void* d_out, int out_size, void* d_ws, size_t ws_size,
                              hipStream_t stream) {
    const float* zp  = (const float*)d_in[0];
    const float* cbp = (const float*)d_in[1];
    float* outp = (float*)d_out;
    float* c2ws = (float*)d_ws;                        // 16384 floats (64 KB)
    half8* frag = (half8*)((float*)d_ws + 16384);      // 4 MB
    float* part = (float*)d_ws + 16384 + 1048576;      // 8192 floats

    pq_frag<<<dim3(64),   dim3(256), 0, stream>>>(cbp, frag, c2ws);
    pq_main<<<dim3(2048), dim3(256), 0, stream>>>(zp, cbp, c2ws, frag, outp, part);
    pq_loss<<<dim3(1),    dim3(256), 0, stream>>>(part, outp);
}